// Round 1
// baseline (329.730 us; speedup 1.0000x reference)
//
#include <hip/hip_runtime.h>
#include <hip/hip_bf16.h>
#include <hip/hip_fp16.h>

// ---------------------------------------------------------------------------
// FakeQuantLinear (Q4_K_M fake-quant + GEMM): out = x @ fq(W)^T + bias
// R7: replace the 1-phase serial GEMM (stage -> drain -> compute, MfmaUtil 46%)
//     with the 256x256 / 8-wave / counted-vmcnt pipeline (T3+T4+T5):
//     K-subtile 32, 4-deep LDS ring (128 KiB), prefetch distance 3 subtiles,
//     2 phases x 16 MFMA per subtile, s_waitcnt vmcnt(8) once per subtile
//     (never 0 in the main loop), raw s_barrier + sched_barrier + setprio.
//     XOR swizzle re-derived for 32-ushort rows: slot s of row r holds chunk
//     s ^ ((r>>1)&3) -> every aligned 8-lane group of ds_read_b128 hits all
//     8 bank-groups (conflict-free, matches R6's measured 0 conflicts).
// ---------------------------------------------------------------------------

typedef __attribute__((ext_vector_type(8))) short bf16x8;    // 8 bf16 = 4 VGPRs
typedef __attribute__((ext_vector_type(8))) unsigned short ushort8;
typedef __attribute__((ext_vector_type(4))) float f32x4;     // MFMA acc

__device__ __forceinline__ unsigned short f2bf(float f) {
  unsigned int u = __float_as_uint(f);
  u += 0x7fffu + ((u >> 16) & 1u);
  return (unsigned short)(u >> 16);
}

// ---------------------------------------------------------------------------
// Fused prep kernel (unchanged from R4/R6).
// ---------------------------------------------------------------------------
__global__ __launch_bounds__(256) void prep_kernel(
    const float* __restrict__ x, unsigned short* __restrict__ xb,
    const float* __restrict__ w, unsigned short* __restrict__ wq,
    int castBlocks) {
  if ((int)blockIdx.x < castBlocks) {
    const size_t i = ((size_t)blockIdx.x * 256 + threadIdx.x) * 8;
    const float4 a = *(const float4*)(x + i);
    const float4 b = *(const float4*)(x + i + 4);
    ushort8 o = {f2bf(a.x), f2bf(a.y), f2bf(a.z), f2bf(a.w),
                 f2bf(b.x), f2bf(b.y), f2bf(b.z), f2bf(b.w)};
    *(ushort8*)(xb + i) = o;
    return;
  }
  const int qb   = blockIdx.x - castBlocks;
  const int lane = threadIdx.x & 63;
  const int wv   = threadIdx.x >> 6;
  const size_t base = (((size_t)qb * 4 + wv) * 256) + (size_t)lane * 4;
  const float4 v = *(const float4*)(w + base);

  float mn = fminf(fminf(v.x, v.y), fminf(v.z, v.w));
  float mx = fmaxf(fmaxf(v.x, v.y), fmaxf(v.z, v.w));
#pragma unroll
  for (int off = 1; off <= 4; off <<= 1) {
    mn = fminf(mn, __shfl_xor(mn, off));
    mx = fmaxf(mx, __shfl_xor(mx, off));
  }
  const float sub_min = fminf(mn, 0.0f);
  const float sub_max = fmaxf(mx, 0.0f);
  const float scale_raw = fmaxf(sub_max - sub_min, 1e-8f) / 15.0f;

  float smn = scale_raw, smx = scale_raw, supermin = sub_min;
#pragma unroll
  for (int off = 8; off <= 32; off <<= 1) {
    smn = fminf(smn, __shfl_xor(smn, off));
    smx = fmaxf(smx, __shfl_xor(smx, off));
    supermin = fminf(supermin, __shfl_xor(supermin, off));
  }
  const float s_range = fmaxf(smx - smn, 1e-8f);
  float s_int = rintf((scale_raw - smn) / s_range * 63.0f);
  s_int = fminf(fmaxf(s_int, 0.0f), 63.0f);
  float scale = s_int / 63.0f * s_range + smn;
  scale = fmaxf(scale, 1e-8f);
  const float inv_scale = 1.0f / scale;

  const float sm  = __half2float(__float2half(supermin));
  const float adj = sub_min - sm;

  float e[4] = {v.x, v.y, v.z, v.w};
  ushort4 o;
  unsigned short* op = (unsigned short*)&o;
#pragma unroll
  for (int k = 0; k < 4; ++k) {
    const float t = (e[k] - sm) - adj;
    float qv = rintf(t * inv_scale);
    qv = fminf(fmaxf(qv, 0.0f), 15.0f);
    op[k] = f2bf((qv * scale + adj) + sm);
  }
  *(ushort4*)(wq + base) = o;
}

// ---------------------------------------------------------------------------
// bf16 MFMA GEMM, C[m,n] = sum_k A[m,k]*B[n,k] + bias[n]
// Block tile 256x256, 512 threads = 8 waves (2M x 4N), wave tile 128x64.
// K-subtile = 32 (one MFMA K-depth). LDS: 4-deep ring of (A 16KiB + B 16KiB)
// subtile buffers = 128 KiB total. Subtile s+3 is staged while computing s;
// per-wave s_waitcnt vmcnt(8) retires exactly subtile s+1's 4 loads (oldest
// outstanding) before the end-of-subtile barrier.
// ---------------------------------------------------------------------------
#define BM 256
#define BN 256
#define BKS 32
#define ABUF 8192   // ushorts per A subtile buffer (256*32)
#define BBUF 8192   // ushorts per B subtile buffer (256*32)

__device__ __forceinline__ void async_cp16(void* lds, const void* g) {
  __builtin_amdgcn_global_load_lds(
      (__attribute__((address_space(1))) void*)(void*)g,
      (__attribute__((address_space(3))) void*)lds, 16, 0, 0);
}

__global__ __launch_bounds__(512, 2) void gemm_bt_kernel(
    const unsigned short* __restrict__ A,   // [M][K] bf16 bits
    const unsigned short* __restrict__ B,   // [N][K] bf16 bits (fq weight)
    const float* __restrict__ bias,         // [N]
    float* __restrict__ C,                  // [M][N] f32
    int M, int N, int K) {
  __shared__ unsigned short lds_a[4 * ABUF];   // 64 KiB
  __shared__ unsigned short lds_b[4 * BBUF];   // 64 KiB

  const int tid  = threadIdx.x;
  const int lane = tid & 63;
  const int wv   = tid >> 6;           // 0..7
  const int wm   = wv >> 2;            // wave row (128 rows each)
  const int wn   = wv & 3;             // wave col (64 cols each)
  const int bx   = blockIdx.x;         // N tile (256)
  const int by   = blockIdx.y;         // M tile (256)

  // --- staging addressing: 512 threads cover 128 rows x 32 cols per issue.
  // thread t -> row t>>2, slot t&3 (LDS off = base + t*16B, wave-uniform+lane).
  // Fetch global chunk (t&3)^((row>>1)&3) so slot s of row r holds s^((r>>1)&3).
  const int rloc = tid >> 2;                       // 0..127
  const int cch  = (tid & 3) ^ ((rloc >> 1) & 3);  // swizzled source chunk
  const int koff = cch * 8;                        // ushort offset in subtile row

  const unsigned short* gA0 = A + (size_t)(by * BM + rloc) * K + koff;
  const unsigned short* gA1 = gA0 + (size_t)128 * K;
  const unsigned short* gB0 = B + (size_t)(bx * BN + rloc) * K + koff;
  const unsigned short* gB1 = gB0 + (size_t)128 * K;

  // --- fragment read addressing: row r = base16 + (lane&15), chunk q = lane>>4.
  // swizzle term ((r>>1)&3) == ((lane&15)>>1)&3 since base16 % 16 == 0.
  const int m16 = lane & 15;
  const int q   = lane >> 4;                       // 0..3
  const int sw  = (m16 >> 1) & 3;
  const int ks  = ((q ^ sw) << 3);                 // ushort offset within row
  const int aoff = (wm * 128 + m16) * BKS + ks;
  const int boff = (wn * 64  + m16) * BKS + ks;

  f32x4 acc[8][4] = {};

  const int nsub = K / BKS;                        // 128

  // --- prologue: stage subtiles 0,1,2 (12 loads/thread), wait subtile 0.
#pragma unroll
  for (int p = 0; p < 3; ++p) {
    const int kof = p * BKS;
    unsigned short* la = lds_a + p * ABUF;
    unsigned short* lb = lds_b + p * BBUF;
    async_cp16(la + tid * 8,        gA0 + kof);
    async_cp16(la + 4096 + tid * 8, gA1 + kof);
    async_cp16(lb + tid * 8,        gB0 + kof);
    async_cp16(lb + 4096 + tid * 8, gB1 + kof);
  }
  asm volatile("s_waitcnt vmcnt(8)" ::: "memory");
  __builtin_amdgcn_s_barrier();
  __builtin_amdgcn_sched_barrier(0);

  for (int s = 0; s < nsub; ++s) {
    const unsigned short* abuf = lds_a + (s & 3) * ABUF;
    const unsigned short* bbuf = lds_b + (s & 3) * BBUF;
    unsigned short* la = lds_a + ((s + 3) & 3) * ABUF;   // slot being refilled
    unsigned short* lb = lds_b + ((s + 3) & 3) * BBUF;
    const int sp  = (s + 3 < nsub) ? (s + 3) : (nsub - 1);  // clamp: keeps
    const int kof = sp * BKS;                               // vmcnt uniform

    // ---------------- phase 0: A rows 0..63 of wave tile ----------------
    bf16x8 af[4], bfr[4];
#pragma unroll
    for (int i = 0; i < 4; ++i)
      af[i] = *(const bf16x8*)(abuf + aoff + i * (16 * BKS));
#pragma unroll
    for (int j = 0; j < 4; ++j)
      bfr[j] = *(const bf16x8*)(bbuf + boff + j * (16 * BKS));
    async_cp16(la + tid * 8,        gA0 + kof);
    async_cp16(la + 4096 + tid * 8, gA1 + kof);
    __builtin_amdgcn_s_barrier();
    __builtin_amdgcn_sched_barrier(0);
    asm volatile("s_waitcnt lgkmcnt(0)" ::: "memory");
    __builtin_amdgcn_sched_barrier(0);
    __builtin_amdgcn_s_setprio(1);
#pragma unroll
    for (int i = 0; i < 4; ++i)
#pragma unroll
      for (int j = 0; j < 4; ++j)
        acc[i][j] = __builtin_amdgcn_mfma_f32_16x16x32_bf16(af[i], bfr[j],
                                                            acc[i][j], 0, 0, 0);
    __builtin_amdgcn_s_setprio(0);
    __builtin_amdgcn_s_barrier();
    __builtin_amdgcn_sched_barrier(0);

    // ---------------- phase 1: A rows 64..127 of wave tile ----------------
    bf16x8 ag[4];
#pragma unroll
    for (int i = 0; i < 4; ++i)
      ag[i] = *(const bf16x8*)(abuf + aoff + (i + 4) * (16 * BKS));
    async_cp16(lb + tid * 8,        gB0 + kof);
    async_cp16(lb + 4096 + tid * 8, gB1 + kof);
    __builtin_amdgcn_s_barrier();
    __builtin_amdgcn_sched_barrier(0);
    asm volatile("s_waitcnt lgkmcnt(0)" ::: "memory");
    __builtin_amdgcn_sched_barrier(0);
    __builtin_amdgcn_s_setprio(1);
#pragma unroll
    for (int i = 0; i < 4; ++i)
#pragma unroll
      for (int j = 0; j < 4; ++j)
        acc[i + 4][j] = __builtin_amdgcn_mfma_f32_16x16x32_bf16(ag[i], bfr[j],
                                                                acc[i + 4][j], 0, 0, 0);
    __builtin_amdgcn_s_setprio(0);
    // 12 loads in flight (s+1,s+2,s+3); retire the 4 oldest (= subtile s+1).
    asm volatile("s_waitcnt vmcnt(8)" ::: "memory");
    __builtin_amdgcn_s_barrier();
    __builtin_amdgcn_sched_barrier(0);
  }

  // Epilogue. C/D layout: col = lane&15, row = (lane>>4)*4 + reg
  const int rbase = by * BM + wm * 128 + (lane >> 4) * 4;
  const int cbase = bx * BN + wn * 64 + m16;
#pragma unroll
  for (int j = 0; j < 4; ++j) {
    const int c = cbase + j * 16;
    const float bv = bias[c];
#pragma unroll
    for (int i = 0; i < 8; ++i) {
#pragma unroll
      for (int r = 0; r < 4; ++r) {
        C[(size_t)(rbase + i * 16 + r) * N + c] = acc[i][j][r] + bv;
      }
    }
  }
}

// ---------------------------------------------------------------------------
extern "C" void kernel_launch(void* const* d_in, const int* in_sizes, int n_in,
                              void* d_out, int out_size, void* d_ws, size_t ws_size,
                              hipStream_t stream) {
  const float* x    = (const float*)d_in[0];
  const float* w    = (const float*)d_in[1];
  const float* bias = (const float*)d_in[2];
  float* out = (float*)d_out;

  const long long xn = in_sizes[0];   // M*K
  const long long wn = in_sizes[1];   // N*K
  const int N = in_sizes[2];
  const int K = (int)(wn / N);
  const int M = (int)(xn / K);

  unsigned short* xb = (unsigned short*)d_ws;
  unsigned short* wb = xb + (size_t)M * K;

  const int castBlocks  = (int)(xn / (256 * 8));    // 8 elems/thread
  const int quantBlocks = (int)(wn / (256 * 4));    // 1024 elems/block
  prep_kernel<<<castBlocks + quantBlocks, 256, 0, stream>>>(x, xb, w, wb,
                                                            castBlocks);
  gemm_bt_kernel<<<dim3(N / BN, M / BM), 512, 0, stream>>>(xb, wb, bias, out,
                                                           M, N, K);
}

// Round 2
// 329.064 us; speedup vs baseline: 1.0020x; 1.0020x over previous
//
#include <hip/hip_runtime.h>
#include <hip/hip_bf16.h>
#include <hip/hip_fp16.h>

// ---------------------------------------------------------------------------
// FakeQuantLinear (Q4_K_M fake-quant + GEMM): out = x @ fq(W)^T + bias
// R8: R7's counted-vmcnt pipeline MINUS the sched_barrier(0) order-pinning.
//     R7 post-mortem: uniform slowdown (MfmaUtil 46->32, VALUBusy 19->12.5,
//     conflicts 0) = serialized schedule, the m141 failure mode. The m201
//     template has NO sched_barriers; compiler-level ds_reads carry their own
//     dependency tracking, and the "memory" clobbers on the vmcnt/lgkmcnt asm
//     already fence the ring-slot refill hazard. Structure kept:
//     256x256 tile, 8 waves (2Mx4N), K-subtile 32, 4-deep LDS ring (128 KiB),
//     prefetch distance 3, s_waitcnt vmcnt(8) once per subtile (never 0),
//     raw s_barrier phase alignment, setprio(1) around MFMA clusters.
// ---------------------------------------------------------------------------

typedef __attribute__((ext_vector_type(8))) short bf16x8;    // 8 bf16 = 4 VGPRs
typedef __attribute__((ext_vector_type(8))) unsigned short ushort8;
typedef __attribute__((ext_vector_type(4))) float f32x4;     // MFMA acc

__device__ __forceinline__ unsigned short f2bf(float f) {
  unsigned int u = __float_as_uint(f);
  u += 0x7fffu + ((u >> 16) & 1u);
  return (unsigned short)(u >> 16);
}

// ---------------------------------------------------------------------------
// Fused prep kernel (unchanged from R4/R6).
// ---------------------------------------------------------------------------
__global__ __launch_bounds__(256) void prep_kernel(
    const float* __restrict__ x, unsigned short* __restrict__ xb,
    const float* __restrict__ w, unsigned short* __restrict__ wq,
    int castBlocks) {
  if ((int)blockIdx.x < castBlocks) {
    const size_t i = ((size_t)blockIdx.x * 256 + threadIdx.x) * 8;
    const float4 a = *(const float4*)(x + i);
    const float4 b = *(const float4*)(x + i + 4);
    ushort8 o = {f2bf(a.x), f2bf(a.y), f2bf(a.z), f2bf(a.w),
                 f2bf(b.x), f2bf(b.y), f2bf(b.z), f2bf(b.w)};
    *(ushort8*)(xb + i) = o;
    return;
  }
  const int qb   = blockIdx.x - castBlocks;
  const int lane = threadIdx.x & 63;
  const int wv   = threadIdx.x >> 6;
  const size_t base = (((size_t)qb * 4 + wv) * 256) + (size_t)lane * 4;
  const float4 v = *(const float4*)(w + base);

  float mn = fminf(fminf(v.x, v.y), fminf(v.z, v.w));
  float mx = fmaxf(fmaxf(v.x, v.y), fmaxf(v.z, v.w));
#pragma unroll
  for (int off = 1; off <= 4; off <<= 1) {
    mn = fminf(mn, __shfl_xor(mn, off));
    mx = fmaxf(mx, __shfl_xor(mx, off));
  }
  const float sub_min = fminf(mn, 0.0f);
  const float sub_max = fmaxf(mx, 0.0f);
  const float scale_raw = fmaxf(sub_max - sub_min, 1e-8f) / 15.0f;

  float smn = scale_raw, smx = scale_raw, supermin = sub_min;
#pragma unroll
  for (int off = 8; off <= 32; off <<= 1) {
    smn = fminf(smn, __shfl_xor(smn, off));
    smx = fmaxf(smx, __shfl_xor(smx, off));
    supermin = fminf(supermin, __shfl_xor(supermin, off));
  }
  const float s_range = fmaxf(smx - smn, 1e-8f);
  float s_int = rintf((scale_raw - smn) / s_range * 63.0f);
  s_int = fminf(fmaxf(s_int, 0.0f), 63.0f);
  float scale = s_int / 63.0f * s_range + smn;
  scale = fmaxf(scale, 1e-8f);
  const float inv_scale = 1.0f / scale;

  const float sm  = __half2float(__float2half(supermin));
  const float adj = sub_min - sm;

  float e[4] = {v.x, v.y, v.z, v.w};
  ushort4 o;
  unsigned short* op = (unsigned short*)&o;
#pragma unroll
  for (int k = 0; k < 4; ++k) {
    const float t = (e[k] - sm) - adj;
    float qv = rintf(t * inv_scale);
    qv = fminf(fmaxf(qv, 0.0f), 15.0f);
    op[k] = f2bf((qv * scale + adj) + sm);
  }
  *(ushort4*)(wq + base) = o;
}

// ---------------------------------------------------------------------------
// bf16 MFMA GEMM, C[m,n] = sum_k A[m,k]*B[n,k] + bias[n]
// Block tile 256x256, 512 threads = 8 waves (2M x 4N), wave tile 128x64.
// K-subtile = 32. LDS: 4-deep ring of (A 16KiB + B 16KiB) = 128 KiB.
// Subtile s+3 staged while computing s; vmcnt(8) at end of subtile s retires
// exactly subtile s+1's 4 loads (oldest outstanding).
// ---------------------------------------------------------------------------
#define BM 256
#define BN 256
#define BKS 32
#define ABUF 8192   // ushorts per A subtile buffer (256*32)
#define BBUF 8192   // ushorts per B subtile buffer (256*32)

__device__ __forceinline__ void async_cp16(void* lds, const void* g) {
  __builtin_amdgcn_global_load_lds(
      (__attribute__((address_space(1))) void*)(void*)g,
      (__attribute__((address_space(3))) void*)lds, 16, 0, 0);
}

__global__ __launch_bounds__(512, 2) void gemm_bt_kernel(
    const unsigned short* __restrict__ A,   // [M][K] bf16 bits
    const unsigned short* __restrict__ B,   // [N][K] bf16 bits (fq weight)
    const float* __restrict__ bias,         // [N]
    float* __restrict__ C,                  // [M][N] f32
    int M, int N, int K) {
  __shared__ unsigned short lds_a[4 * ABUF];   // 64 KiB
  __shared__ unsigned short lds_b[4 * BBUF];   // 64 KiB

  const int tid  = threadIdx.x;
  const int lane = tid & 63;
  const int wv   = tid >> 6;           // 0..7
  const int wm   = wv >> 2;            // wave row (128 rows each)
  const int wn   = wv & 3;             // wave col (64 cols each)
  const int bx   = blockIdx.x;         // N tile (256)
  const int by   = blockIdx.y;         // M tile (256)

  // --- staging addressing: 512 threads cover 128 rows x 32 cols per issue.
  // thread t -> row t>>2, slot t&3 (LDS off = base + t*16B, wave-uniform+lane).
  // Fetch global chunk (t&3)^((row>>1)&3) so slot s of row r holds s^((r>>1)&3).
  const int rloc = tid >> 2;                       // 0..127
  const int cch  = (tid & 3) ^ ((rloc >> 1) & 3);  // swizzled source chunk
  const int koff = cch * 8;                        // ushort offset in subtile row

  const unsigned short* gA0 = A + (size_t)(by * BM + rloc) * K + koff;
  const unsigned short* gA1 = gA0 + (size_t)128 * K;
  const unsigned short* gB0 = B + (size_t)(bx * BN + rloc) * K + koff;
  const unsigned short* gB1 = gB0 + (size_t)128 * K;

  // --- fragment read addressing: row r = base16 + (lane&15), chunk q = lane>>4.
  // swizzle term ((r>>1)&3) == ((lane&15)>>1)&3 since base16 % 16 == 0.
  const int m16 = lane & 15;
  const int q   = lane >> 4;                       // 0..3
  const int sw  = (m16 >> 1) & 3;
  const int ks  = ((q ^ sw) << 3);                 // ushort offset within row
  const int aoff = (wm * 128 + m16) * BKS + ks;
  const int boff = (wn * 64  + m16) * BKS + ks;

  f32x4 acc[8][4] = {};

  const int nsub = K / BKS;                        // 128

  // --- prologue: stage subtiles 0,1,2 (12 loads/thread), wait subtile 0.
#pragma unroll
  for (int p = 0; p < 3; ++p) {
    const int kof = p * BKS;
    unsigned short* la = lds_a + p * ABUF;
    unsigned short* lb = lds_b + p * BBUF;
    async_cp16(la + tid * 8,        gA0 + kof);
    async_cp16(la + 4096 + tid * 8, gA1 + kof);
    async_cp16(lb + tid * 8,        gB0 + kof);
    async_cp16(lb + 4096 + tid * 8, gB1 + kof);
  }
  asm volatile("s_waitcnt vmcnt(8)" ::: "memory");
  __builtin_amdgcn_s_barrier();

  for (int s = 0; s < nsub; ++s) {
    const unsigned short* abuf = lds_a + (s & 3) * ABUF;
    const unsigned short* bbuf = lds_b + (s & 3) * BBUF;
    unsigned short* la = lds_a + ((s + 3) & 3) * ABUF;   // slot being refilled
    unsigned short* lb = lds_b + ((s + 3) & 3) * BBUF;
    const int sp  = (s + 3 < nsub) ? (s + 3) : (nsub - 1);  // clamp: keeps
    const int kof = sp * BKS;                               // vmcnt uniform

    // ---------------- phase 0: A rows 0..63 of wave tile ----------------
    bf16x8 af[4], bfr[4];
#pragma unroll
    for (int i = 0; i < 4; ++i)
      af[i] = *(const bf16x8*)(abuf + aoff + i * (16 * BKS));
#pragma unroll
    for (int j = 0; j < 4; ++j)
      bfr[j] = *(const bf16x8*)(bbuf + boff + j * (16 * BKS));
    async_cp16(la + tid * 8,        gA0 + kof);
    async_cp16(la + 4096 + tid * 8, gA1 + kof);
    __builtin_amdgcn_s_barrier();
    asm volatile("s_waitcnt lgkmcnt(0)" ::: "memory");
    __builtin_amdgcn_s_setprio(1);
#pragma unroll
    for (int i = 0; i < 4; ++i)
#pragma unroll
      for (int j = 0; j < 4; ++j)
        acc[i][j] = __builtin_amdgcn_mfma_f32_16x16x32_bf16(af[i], bfr[j],
                                                            acc[i][j], 0, 0, 0);
    __builtin_amdgcn_s_setprio(0);
    __builtin_amdgcn_s_barrier();

    // ---------------- phase 1: A rows 64..127 of wave tile ----------------
    bf16x8 ag[4];
#pragma unroll
    for (int i = 0; i < 4; ++i)
      ag[i] = *(const bf16x8*)(abuf + aoff + (i + 4) * (16 * BKS));
    async_cp16(lb + tid * 8,        gB0 + kof);
    async_cp16(lb + 4096 + tid * 8, gB1 + kof);
    __builtin_amdgcn_s_barrier();
    asm volatile("s_waitcnt lgkmcnt(0)" ::: "memory");
    __builtin_amdgcn_s_setprio(1);
#pragma unroll
    for (int i = 0; i < 4; ++i)
#pragma unroll
      for (int j = 0; j < 4; ++j)
        acc[i + 4][j] = __builtin_amdgcn_mfma_f32_16x16x32_bf16(ag[i], bfr[j],
                                                                acc[i + 4][j], 0, 0, 0);
    __builtin_amdgcn_s_setprio(0);
    // 12 loads in flight (s+1,s+2,s+3); retire the 4 oldest (= subtile s+1).
    asm volatile("s_waitcnt vmcnt(8)" ::: "memory");
    __builtin_amdgcn_s_barrier();
  }

  // Epilogue. C/D layout: col = lane&15, row = (lane>>4)*4 + reg
  const int rbase = by * BM + wm * 128 + (lane >> 4) * 4;
  const int cbase = bx * BN + wn * 64 + m16;
#pragma unroll
  for (int j = 0; j < 4; ++j) {
    const int c = cbase + j * 16;
    const float bv = bias[c];
#pragma unroll
    for (int i = 0; i < 8; ++i) {
#pragma unroll
      for (int r = 0; r < 4; ++r) {
        C[(size_t)(rbase + i * 16 + r) * N + c] = acc[i][j][r] + bv;
      }
    }
  }
}

// ---------------------------------------------------------------------------
extern "C" void kernel_launch(void* const* d_in, const int* in_sizes, int n_in,
                              void* d_out, int out_size, void* d_ws, size_t ws_size,
                              hipStream_t stream) {
  const float* x    = (const float*)d_in[0];
  const float* w    = (const float*)d_in[1];
  const float* bias = (const float*)d_in[2];
  float* out = (float*)d_out;

  const long long xn = in_sizes[0];   // M*K
  const long long wn = in_sizes[1];   // N*K
  const int N = in_sizes[2];
  const int K = (int)(wn / N);
  const int M = (int)(xn / K);

  unsigned short* xb = (unsigned short*)d_ws;
  unsigned short* wb = xb + (size_t)M * K;

  const int castBlocks  = (int)(xn / (256 * 8));    // 8 elems/thread
  const int quantBlocks = (int)(wn / (256 * 4));    // 1024 elems/block
  prep_kernel<<<castBlocks + quantBlocks, 256, 0, stream>>>(x, xb, w, wb,
                                                            castBlocks);
  gemm_bt_kernel<<<dim3(N / BN, M / BM), 512, 0, stream>>>(xb, wb, bias, out,
                                                           M, N, K);
}

// Round 3
// 308.922 us; speedup vs baseline: 1.0674x; 1.0652x over previous
//
#include <hip/hip_runtime.h>
#include <hip/hip_bf16.h>
#include <hip/hip_fp16.h>

// ---------------------------------------------------------------------------
// FakeQuantLinear (Q4_K_M fake-quant + GEMM): out = x @ fq(W)^T + bias
// R9: R8 post-mortem showed the R7/R8 regression is the single 8-wave barrier
//     domain (1 block/CU @ 128 KiB LDS), not scheduling: R6's 2 blocks/CU gave
//     inter-block MFMA/stall overlap (m114). R9 keeps the counted-vmcnt ring
//     pipeline but restores 2 independent blocks/CU:
//       256x128 tile, 256 thr (4 waves 2x2, wave tile 128x64), BKS=32,
//       3-deep LDS ring (72 KiB -> 2 blocks/CU), prefetch distance 2,
//       6 global_load_lds per subtile, s_waitcnt vmcnt(6) once per subtile
//       (never 0 in-loop), ONE s_barrier per subtile, setprio around the
//       32-MFMA cluster. Hazards: refill target buf[(s+2)%3]=buf[(s-1)%3]
//       freed by the end-of-(s-1) barrier; buf[s+1] loads retired by all
//       waves' vmcnt(6) before the end-of-s barrier.
// ---------------------------------------------------------------------------

typedef __attribute__((ext_vector_type(8))) short bf16x8;    // 8 bf16 = 4 VGPRs
typedef __attribute__((ext_vector_type(8))) unsigned short ushort8;
typedef __attribute__((ext_vector_type(4))) float f32x4;     // MFMA acc

__device__ __forceinline__ unsigned short f2bf(float f) {
  unsigned int u = __float_as_uint(f);
  u += 0x7fffu + ((u >> 16) & 1u);
  return (unsigned short)(u >> 16);
}

// ---------------------------------------------------------------------------
// Fused prep kernel (unchanged from R4/R6).
// ---------------------------------------------------------------------------
__global__ __launch_bounds__(256) void prep_kernel(
    const float* __restrict__ x, unsigned short* __restrict__ xb,
    const float* __restrict__ w, unsigned short* __restrict__ wq,
    int castBlocks) {
  if ((int)blockIdx.x < castBlocks) {
    const size_t i = ((size_t)blockIdx.x * 256 + threadIdx.x) * 8;
    const float4 a = *(const float4*)(x + i);
    const float4 b = *(const float4*)(x + i + 4);
    ushort8 o = {f2bf(a.x), f2bf(a.y), f2bf(a.z), f2bf(a.w),
                 f2bf(b.x), f2bf(b.y), f2bf(b.z), f2bf(b.w)};
    *(ushort8*)(xb + i) = o;
    return;
  }
  const int qb   = blockIdx.x - castBlocks;
  const int lane = threadIdx.x & 63;
  const int wv   = threadIdx.x >> 6;
  const size_t base = (((size_t)qb * 4 + wv) * 256) + (size_t)lane * 4;
  const float4 v = *(const float4*)(w + base);

  float mn = fminf(fminf(v.x, v.y), fminf(v.z, v.w));
  float mx = fmaxf(fmaxf(v.x, v.y), fmaxf(v.z, v.w));
#pragma unroll
  for (int off = 1; off <= 4; off <<= 1) {
    mn = fminf(mn, __shfl_xor(mn, off));
    mx = fmaxf(mx, __shfl_xor(mx, off));
  }
  const float sub_min = fminf(mn, 0.0f);
  const float sub_max = fmaxf(mx, 0.0f);
  const float scale_raw = fmaxf(sub_max - sub_min, 1e-8f) / 15.0f;

  float smn = scale_raw, smx = scale_raw, supermin = sub_min;
#pragma unroll
  for (int off = 8; off <= 32; off <<= 1) {
    smn = fminf(smn, __shfl_xor(smn, off));
    smx = fmaxf(smx, __shfl_xor(smx, off));
    supermin = fminf(supermin, __shfl_xor(supermin, off));
  }
  const float s_range = fmaxf(smx - smn, 1e-8f);
  float s_int = rintf((scale_raw - smn) / s_range * 63.0f);
  s_int = fminf(fmaxf(s_int, 0.0f), 63.0f);
  float scale = s_int / 63.0f * s_range + smn;
  scale = fmaxf(scale, 1e-8f);
  const float inv_scale = 1.0f / scale;

  const float sm  = __half2float(__float2half(supermin));
  const float adj = sub_min - sm;

  float e[4] = {v.x, v.y, v.z, v.w};
  ushort4 o;
  unsigned short* op = (unsigned short*)&o;
#pragma unroll
  for (int k = 0; k < 4; ++k) {
    const float t = (e[k] - sm) - adj;
    float qv = rintf(t * inv_scale);
    qv = fminf(fmaxf(qv, 0.0f), 15.0f);
    op[k] = f2bf((qv * scale + adj) + sm);
  }
  *(ushort4*)(wq + base) = o;
}

// ---------------------------------------------------------------------------
// bf16 MFMA GEMM, C[m,n] = sum_k A[m,k]*B[n,k] + bias[n]
// Block tile 256x128, 256 threads = 4 waves (2M x 2N), wave tile 128x64.
// K-subtile = 32. LDS ring of 3 x (A 16KiB + B 8KiB) = 72 KiB -> 2 blocks/CU.
// Subtile s+2 staged while computing s; vmcnt(6) at end of subtile s retires
// exactly subtile s+1's 6 loads (oldest outstanding).
// ---------------------------------------------------------------------------
#define BM 256
#define BN 128
#define BKS 32
#define ABUF 8192   // ushorts per A subtile buffer (256*32)
#define BBUF 4096   // ushorts per B subtile buffer (128*32)

__device__ __forceinline__ void async_cp16(void* lds, const void* g) {
  __builtin_amdgcn_global_load_lds(
      (__attribute__((address_space(1))) void*)(void*)g,
      (__attribute__((address_space(3))) void*)lds, 16, 0, 0);
}

__global__ __launch_bounds__(256, 2) void gemm_bt_kernel(
    const unsigned short* __restrict__ A,   // [M][K] bf16 bits
    const unsigned short* __restrict__ B,   // [N][K] bf16 bits (fq weight)
    const float* __restrict__ bias,         // [N]
    float* __restrict__ C,                  // [M][N] f32
    int M, int N, int K) {
  __shared__ unsigned short lds_a[3 * ABUF];   // 48 KiB
  __shared__ unsigned short lds_b[3 * BBUF];   // 24 KiB

  const int tid  = threadIdx.x;
  const int lane = tid & 63;
  const int wv   = tid >> 6;           // 0..3
  const int wm   = wv >> 1;            // wave row (128 rows each)
  const int wn   = wv & 1;             // wave col (64 cols each)
  const int bx   = blockIdx.x;         // N tile (128)
  const int by   = blockIdx.y;         // M tile (256)

  // --- staging: per issue, 256 threads cover 64 rows x 32 cols (16B/thread).
  // thread t -> row j*64 + (t>>2), slot t&3 (LDS off = base + t*16B).
  // Fetch global chunk (t&3)^((row>>1)&3) = (t&3)^((t>>3)&3) so slot s of
  // row r holds chunk s^((r>>1)&3) (conflict-free readers, 0 conflicts in R8).
  const int rr   = tid >> 2;                       // 0..63
  const int cch  = (tid & 3) ^ ((tid >> 3) & 3);   // swizzled source chunk
  const int koff = cch * 8;                        // ushort offset in row

  const unsigned short* gA[4];
  const unsigned short* gB[2];
#pragma unroll
  for (int j = 0; j < 4; ++j)
    gA[j] = A + (size_t)(by * BM + j * 64 + rr) * K + koff;
#pragma unroll
  for (int j = 0; j < 2; ++j)
    gB[j] = B + (size_t)(bx * BN + j * 64 + rr) * K + koff;

  // --- fragment read addressing: row r = base16 + (lane&15), chunk q = lane>>4.
  // swizzle term ((r>>1)&3) == ((m16>>1)&3) since base16 % 16 == 0.
  const int m16 = lane & 15;
  const int q   = lane >> 4;                       // 0..3
  const int sw  = (m16 >> 1) & 3;
  const int ks  = ((q ^ sw) << 3);                 // ushort offset within row
  const int aoff = (wm * 128 + m16) * BKS + ks;
  const int boff = (wn * 64  + m16) * BKS + ks;

  f32x4 acc[8][4] = {};

  const int nsub = K / BKS;                        // 128

  // --- prologue: stage subtiles 0 -> buf0, 1 -> buf1 (12 loads/thread).
#pragma unroll
  for (int p = 0; p < 2; ++p) {
    unsigned short* la = lds_a + p * ABUF;
    unsigned short* lb = lds_b + p * BBUF;
    const int kof = p * BKS;
#pragma unroll
    for (int j = 0; j < 4; ++j) async_cp16(la + j * 2048 + tid * 8, gA[j] + kof);
#pragma unroll
    for (int j = 0; j < 2; ++j) async_cp16(lb + j * 2048 + tid * 8, gB[j] + kof);
  }
  asm volatile("s_waitcnt vmcnt(6)" ::: "memory");   // subtile 0 resident
  __builtin_amdgcn_s_barrier();

  int rb = 0;      // ring index being read (s%3)
  int wr = 2;      // ring index being refilled ((s+2)%3)
  for (int s = 0; s < nsub; ++s) {
    const unsigned short* abuf = lds_a + rb * ABUF;
    const unsigned short* bbuf = lds_b + rb * BBUF;
    unsigned short* la = lds_a + wr * ABUF;
    unsigned short* lb = lds_b + wr * BBUF;
    const int sp  = (s + 2 < nsub) ? (s + 2) : (nsub - 1);  // clamp keeps
    const int kof = sp * BKS;                               // vmcnt uniform

    // issue next-next subtile's loads first (max latency overlap)
#pragma unroll
    for (int j = 0; j < 4; ++j) async_cp16(la + j * 2048 + tid * 8, gA[j] + kof);
#pragma unroll
    for (int j = 0; j < 2; ++j) async_cp16(lb + j * 2048 + tid * 8, gB[j] + kof);

    // fragment loads from current buffer (compiler emits fine-grained lgkm
    // waits interleaving these with the first MFMAs)
    bf16x8 af[8], bfr[4];
#pragma unroll
    for (int i = 0; i < 8; ++i)
      af[i] = *(const bf16x8*)(abuf + aoff + i * (16 * BKS));
#pragma unroll
    for (int j = 0; j < 4; ++j)
      bfr[j] = *(const bf16x8*)(bbuf + boff + j * (16 * BKS));

    __builtin_amdgcn_s_setprio(1);
#pragma unroll
    for (int i = 0; i < 8; ++i)
#pragma unroll
      for (int j = 0; j < 4; ++j)
        acc[i][j] = __builtin_amdgcn_mfma_f32_16x16x32_bf16(af[i], bfr[j],
                                                            acc[i][j], 0, 0, 0);
    __builtin_amdgcn_s_setprio(0);

    // 12 loads in flight (s+1, s+2); retire the 6 oldest (= subtile s+1),
    // then the barrier makes that true for ALL waves of the block.
    asm volatile("s_waitcnt vmcnt(6)" ::: "memory");
    __builtin_amdgcn_s_barrier();

    rb = (rb == 2) ? 0 : rb + 1;
    wr = (wr == 2) ? 0 : wr + 1;
  }

  // Epilogue. C/D layout: col = lane&15, row = (lane>>4)*4 + reg
  const int rbase = by * BM + wm * 128 + (lane >> 4) * 4;
  const int cbase = bx * BN + wn * 64 + m16;
#pragma unroll
  for (int j = 0; j < 4; ++j) {
    const int c = cbase + j * 16;
    const float bv = bias[c];
#pragma unroll
    for (int i = 0; i < 8; ++i) {
#pragma unroll
      for (int r = 0; r < 4; ++r) {
        C[(size_t)(rbase + i * 16 + r) * N + c] = acc[i][j][r] + bv;
      }
    }
  }
}

// ---------------------------------------------------------------------------
extern "C" void kernel_launch(void* const* d_in, const int* in_sizes, int n_in,
                              void* d_out, int out_size, void* d_ws, size_t ws_size,
                              hipStream_t stream) {
  const float* x    = (const float*)d_in[0];
  const float* w    = (const float*)d_in[1];
  const float* bias = (const float*)d_in[2];
  float* out = (float*)d_out;

  const long long xn = in_sizes[0];   // M*K
  const long long wn = in_sizes[1];   // N*K
  const int N = in_sizes[2];
  const int K = (int)(wn / N);
  const int M = (int)(xn / K);

  unsigned short* xb = (unsigned short*)d_ws;
  unsigned short* wb = xb + (size_t)M * K;

  const int castBlocks  = (int)(xn / (256 * 8));    // 8 elems/thread
  const int quantBlocks = (int)(wn / (256 * 4));    // 1024 elems/block
  prep_kernel<<<castBlocks + quantBlocks, 256, 0, stream>>>(x, xb, w, wb,
                                                            castBlocks);
  gemm_bt_kernel<<<dim3(N / BN, M / BM), 256, 0, stream>>>(xb, wb, bias, out,
                                                           M, N, K);
}